// Round 7
// baseline (58.791 us; speedup 1.0000x reference)
//
#include <hip/hip_runtime.h>
#include <math.h>

#define IMG_H 512
#define IMG_W 512
#define CH    3
#define BX    16                 // tile width (threads x)
#define TYB   8                  // threads y; each owns 2 rows
#define TILE_H 16
#define PAD   2
#define TP    20                 // padded tile dim (both axes)

typedef float v2f __attribute__((ext_vector_type(2)));

#if __has_builtin(__builtin_amdgcn_exp2f)
#define EXP2(x) __builtin_amdgcn_exp2f(x)
#else
#define EXP2(x) exp2f(x)
#endif

#if __has_builtin(__builtin_amdgcn_rcpf)
#define RCP(x) __builtin_amdgcn_rcpf(x)
#else
#define RCP(x) (1.0f / (x))
#endif

__device__ __forceinline__ int reflect_idx(int i, int n) {
    i = (i < 0) ? -i : i;
    i = (i >= n) ? (2 * n - 2 - i) : i;
    return i;
}

__global__ __launch_bounds__(128)
void bilateral_kernel(const float* __restrict__ in, float* __restrict__ out) {
    // Entry: {r*S, g*S, b*S, -||s*S||^2}, S^2 = 312.5 * log2(e).
    // Conflict-free law (R3/R6 measured 0): a wave's four 16-lane groups must
    // read rows 4 apart at stride 20-float4. Achieved via rstart permutation.
    __shared__ float4 lds[TP][TP];   // 6.4 KB

    const float S = sqrtf(312.5f * 1.44269504088896f);  // compile-time folded

    const int b  = blockIdx.z;
    const int by = blockIdx.y * TILE_H;
    const int bx = blockIdx.x * BX;
    const int tx = threadIdx.x;
    const int ty = threadIdx.y;
    const int tid = ty * BX + tx;

    // Cooperative halo staging with reflect padding (400 entries, 128 thr).
    for (int i = tid; i < TP * TP; i += BX * TYB) {
        const int py = i / TP;
        const int px = i - py * TP;
        const int gy = reflect_idx(by + py - PAD, IMG_H);
        const int gx = reflect_idx(bx + px - PAD, IMG_W);
        const float* src = in + ((size_t)(b * IMG_H + gy) * IMG_W + gx) * CH;
        const float s0 = src[0] * S;
        const float s1 = src[1] * S;
        const float s2 = src[2] * S;
        const float mq = -fmaf(s0, s0, fmaf(s1, s1, s2 * s2));
        ((float4*)lds)[i] = make_float4(s0, s1, s2, mq);
    }
    __syncthreads();

    // Row permutation: wave = ty 0..3 (or 4..7); groups land on row-pairs
    // starting {0,4,8,12} ({2,6,10,14}) -> 4-apart geometry, conflict-free.
    const int rstart = ((ty & 3) << 2) | ((ty >> 2) << 1);

    // log2 of normalized 1-D gaussian weights, index min(d, 4-d).
    const float CW[3] = { -4.1978935f, -2.0338538f, -1.3125121f };

    // Two centers per thread: padded rows rstart+2+j, col tx+2.
    v2f   c01[2], c2z1[2];
    float cwd[2][3];
    #pragma unroll
    for (int j = 0; j < 2; ++j) {
        const float4 c = lds[rstart + 2 + j][tx + PAD];
        c01[j]  = (v2f){ c.x + c.x, c.y + c.y };
        c2z1[j] = (v2f){ c.z + c.z, 1.0f };
        cwd[j][0] = c.w + CW[0];
        cwd[j][1] = c.w + CW[1];
        cwd[j][2] = c.w + CW[2];
    }

    v2f   nxy[2] = { (v2f){0.f, 0.f}, (v2f){0.f, 0.f} };
    float n2[2]  = { 0.f, 0.f };
    float den[2] = { 0.f, 0.f };

    // 6 window rows serve both centers (center j uses window rows j..j+4).
    #pragma unroll
    for (int r = 0; r < 6; ++r) {
        #pragma unroll
        for (int k = 0; k < 5; ++k) {
            const float4 s = lds[rstart + r][tx + k];
            const float swk = s.w + CW[k < 3 ? k : 4 - k];  // shared by centers
            const v2f sxy = (v2f){ s.x, s.y };
            #pragma unroll
            for (int j = 0; j < 2; ++j) {
                const int dy = r - j;
                if (dy < 0 || dy > 4) continue;   // compile-time pruned
                const v2f base0 = (v2f){ cwd[j][dy < 3 ? dy : 4 - dy], 0.0f };
                const v2f szw = (v2f){ s.z, swk };
                const v2f q = __builtin_elementwise_fma(szw, c2z1[j], base0);
                const v2f p = __builtin_elementwise_fma(sxy, c01[j], q);
                const float w = EXP2(p.x + p.y);
                nxy[j] = __builtin_elementwise_fma((v2f){ w, w }, sxy, nxy[j]);
                n2[j]  = fmaf(w, s.z, n2[j]);
                den[j] += w;
            }
        }
    }

    #pragma unroll
    for (int j = 0; j < 2; ++j) {
        const float inv = RCP(den[j] * S);
        const int y = by + rstart + j;
        float* dst = out + ((size_t)(b * IMG_H + y) * IMG_W + (bx + tx)) * CH;
        dst[0] = fminf(fmaxf(nxy[j].x * inv, 0.0f), 1.0f);
        dst[1] = fminf(fmaxf(nxy[j].y * inv, 0.0f), 1.0f);
        dst[2] = fminf(fmaxf(n2[j]  * inv, 0.0f), 1.0f);
    }
}

extern "C" void kernel_launch(void* const* d_in, const int* in_sizes, int n_in,
                              void* d_out, int out_size, void* d_ws, size_t ws_size,
                              hipStream_t stream) {
    const float* in = (const float*)d_in[0];
    float* out = (float*)d_out;
    const int B = in_sizes[0] / (IMG_H * IMG_W * CH);   // 16

    dim3 block(BX, TYB, 1);
    dim3 grid(IMG_W / BX, IMG_H / TILE_H, B);           // 32 x 32 x 16
    bilateral_kernel<<<grid, block, 0, stream>>>(in, out);
}

// Round 8
// 47.623 us; speedup vs baseline: 1.2345x; 1.2345x over previous
//
#include <hip/hip_runtime.h>
#include <math.h>

#define IMG_H 512
#define IMG_W 512
#define CH    3
#define BX    16                 // threads x
#define TYN   16                 // threads y; each owns 2 output rows
#define TILE_H 32
#define PAD   2
#define TPW   20                 // padded tile width (float4 entries)
#define TPH   36                 // padded tile height

typedef float v2f __attribute__((ext_vector_type(2)));

#if __has_builtin(__builtin_amdgcn_exp2f)
#define EXP2(x) __builtin_amdgcn_exp2f(x)
#else
#define EXP2(x) exp2f(x)
#endif

#if __has_builtin(__builtin_amdgcn_rcpf)
#define RCP(x) __builtin_amdgcn_rcpf(x)
#else
#define RCP(x) (1.0f / (x))
#endif

__device__ __forceinline__ int reflect_idx(int i, int n) {
    i = (i < 0) ? -i : i;
    i = (i >= n) ? (2 * n - 2 - i) : i;
    return i;
}

__global__ __launch_bounds__(256)
void bilateral_kernel(const float* __restrict__ in, float* __restrict__ out) {
    // Entry: {r*S, g*S, b*S, -||s*S||^2}, S^2 = 312.5 * log2(e).
    // Conflict-free law (R3/R6/R7 measured 0): wave's four 16-lane groups read
    // rows 4 apart at stride 20 float4. Row permutation below enforces it.
    __shared__ float4 lds[TPH][TPW];   // 11.52 KB

    const float S = sqrtf(312.5f * 1.44269504088896f);  // compile-time folded

    const int b  = blockIdx.z;
    const int by = blockIdx.y * TILE_H;
    const int bx = blockIdx.x * BX;
    const int tx = threadIdx.x;
    const int ty = threadIdx.y;
    const int tid = ty * BX + tx;

    // Cooperative halo staging with reflect padding (720 entries, 3 iters).
    for (int i = tid; i < TPH * TPW; i += BX * TYN) {
        const int py = i / TPW;
        const int px = i - py * TPW;
        const int gy = reflect_idx(by + py - PAD, IMG_H);
        const int gx = reflect_idx(bx + px - PAD, IMG_W);
        const float* src = in + ((size_t)(b * IMG_H + gy) * IMG_W + gx) * CH;
        const float s0 = src[0] * S;
        const float s1 = src[1] * S;
        const float s2 = src[2] * S;
        const float mq = -fmaf(s0, s0, fmaf(s1, s1, s2 * s2));
        ((float4*)lds)[i] = make_float4(s0, s1, s2, mq);
    }
    __syncthreads();

    // Row permutation: wave w (ty = 4w..4w+3) owns row-pairs starting at
    // base_w + {0,4,8,12}, base_w in {0,2,16,18}. Lane groups stay 4 apart.
    const int rstart = ((ty >> 3) << 4) | (((ty >> 2) & 1) << 1) | ((ty & 3) << 2);

    // log2 gaussian: CW(d) = A + Q*(d-2)^2, A = -1.3125121, Q = -0.72134752.
    const float A2 = -2.625024f;            // 2*A (row + col constant parts)
    const float Q  = -0.72134752f;
    const float QK0 = Q * 4.0f;             // col terms, static per k
    const float QK1 = Q;

    // Two centers: padded rows rstart+2+j, col tx+2.
    v2f   c01[2], c2z1[2];
    float cwA[2];
    #pragma unroll
    for (int j = 0; j < 2; ++j) {
        const float4 c = lds[rstart + 2 + j][tx + PAD];
        c01[j]  = (v2f){ c.x + c.x, c.y + c.y };
        c2z1[j] = (v2f){ c.z + c.z, 1.0f };
        cwA[j]  = c.w + A2;
    }

    v2f nxy[2]   = { (v2f){0.f, 0.f}, (v2f){0.f, 0.f} };
    v2f nzden[2] = { (v2f){0.f, 0.f}, (v2f){0.f, 0.f} };

    // 6 window rows serve both centers; NOT unrolled so only 5 loads in
    // flight -> live set stays small (R7's 112-VGPR lesson).
    #pragma unroll 1
    for (int r = 0; r < 6; ++r) {
        const float t0 = (float)(r - 2);
        const float t1 = (float)(r - 3);
        float b0 = fmaf(Q, t0 * t0, cwA[0]);
        float b1 = fmaf(Q, t1 * t1, cwA[1]);
        b0 = (r <= 4) ? b0 : -60000.0f;   // uniform select; exp2 -> 0
        b1 = (r >= 1) ? b1 : -60000.0f;
        const float4* row = &lds[rstart + r][tx];

        #pragma unroll
        for (int k = 0; k < 5; ++k) {
            const float4 s = row[k];
            const float qk = (k == 2) ? 0.0f : ((k == 1 || k == 3) ? QK1 : QK0);
            const float swk = s.w + qk;            // shared by both centers
            const v2f sxy = (v2f){ s.x, s.y };
            const v2f szw = (v2f){ s.z, swk };
            const v2f sz1 = (v2f){ s.z, 1.0f };
            #pragma unroll
            for (int j = 0; j < 2; ++j) {
                const v2f base = (v2f){ (j == 0) ? b0 : b1, 0.0f };
                const v2f q = __builtin_elementwise_fma(szw, c2z1[j], base);
                const v2f p = __builtin_elementwise_fma(sxy, c01[j], q);
                const float w = EXP2(p.x + p.y);
                const v2f w2 = (v2f){ w, w };
                nxy[j]   = __builtin_elementwise_fma(w2, sxy, nxy[j]);
                nzden[j] = __builtin_elementwise_fma(w2, sz1, nzden[j]);
            }
        }
    }

    #pragma unroll
    for (int j = 0; j < 2; ++j) {
        const float inv = RCP(nzden[j].y * S);
        const int y = by + rstart + j;
        float* dst = out + ((size_t)(b * IMG_H + y) * IMG_W + (bx + tx)) * CH;
        dst[0] = fminf(fmaxf(nxy[j].x   * inv, 0.0f), 1.0f);
        dst[1] = fminf(fmaxf(nxy[j].y   * inv, 0.0f), 1.0f);
        dst[2] = fminf(fmaxf(nzden[j].x * inv, 0.0f), 1.0f);
    }
}

extern "C" void kernel_launch(void* const* d_in, const int* in_sizes, int n_in,
                              void* d_out, int out_size, void* d_ws, size_t ws_size,
                              hipStream_t stream) {
    const float* in = (const float*)d_in[0];
    float* out = (float*)d_out;
    const int B = in_sizes[0] / (IMG_H * IMG_W * CH);   // 16

    dim3 block(BX, TYN, 1);
    dim3 grid(IMG_W / BX, IMG_H / TILE_H, B);           // 32 x 16 x 16
    bilateral_kernel<<<grid, block, 0, stream>>>(in, out);
}

// Round 9
// 42.537 us; speedup vs baseline: 1.3821x; 1.1196x over previous
//
#include <hip/hip_runtime.h>
#include <math.h>

#define IMG_H 512
#define IMG_W 512
#define CH    3
#define TILE  16
#define PAD   2
#define TP    (TILE + 2 * PAD)   // 20

typedef float v2f __attribute__((ext_vector_type(2)));

#if __has_builtin(__builtin_amdgcn_exp2f)
#define EXP2(x) __builtin_amdgcn_exp2f(x)
#else
#define EXP2(x) exp2f(x)
#endif

#if __has_builtin(__builtin_amdgcn_rcpf)
#define RCP(x) __builtin_amdgcn_rcpf(x)
#else
#define RCP(x) (1.0f / (x))
#endif

__device__ __forceinline__ int reflect_idx(int i, int n) {
    i = (i < 0) ? -i : i;
    i = (i >= n) ? (2 * n - 2 - i) : i;
    return i;
}

__global__ __launch_bounds__(256)
void bilateral_kernel(const float* __restrict__ in, float* __restrict__ out) {
    // Entry: {r*S, g*S, b*S, -||s*S||^2}, S^2 = 312.5 * log2(e).
    // Conflict-free law (R3/R6/R7/R8 measured 0): wave's four 16-lane groups
    // read rows 4 apart at stride 20 float4, via the rp permutation.
    __shared__ float4 lds[TP][TP];

    const float S = sqrtf(312.5f * 1.44269504088896f);  // compile-time folded

    const int b  = blockIdx.z;
    const int by = blockIdx.y * TILE;
    const int bx = blockIdx.x * TILE;
    const int tx = threadIdx.x;
    const int ty = threadIdx.y;
    const int tid = ty * TILE + tx;

    // Cooperative halo staging with reflect padding (400 entries, 2 iters).
    for (int i = tid; i < TP * TP; i += 256) {
        const int py = i / TP;
        const int px = i - py * TP;
        const int gy = reflect_idx(by + py - PAD, IMG_H);
        const int gx = reflect_idx(bx + px - PAD, IMG_W);
        const float* src = in + ((size_t)(b * IMG_H + gy) * IMG_W + gx) * CH;
        const float s0 = src[0] * S;
        const float s1 = src[1] * S;
        const float s2 = src[2] * S;
        const float mq = -fmaf(s0, s0, fmaf(s1, s1, s2 * s2));
        ((float4*)lds)[i] = make_float4(s0, s1, s2, mq);
    }
    __syncthreads();

    // Row permutation: ty 0..3 -> rows 0,4,8,12 within each wave.
    const int rp = ((ty & 3) << 2) | (ty >> 2);

    // log2 of normalized 1-D gaussian weights, index min(d, 4-d).
    const float CW[3] = { -4.1978935f, -2.0338538f, -1.3125121f };

    const float4 c = lds[rp + PAD][tx + PAD];
    const v2f c01  = (v2f){ c.x + c.x, c.y + c.y };
    const v2f c2z1 = (v2f){ c.z + c.z, 1.0f };

    // 9 fully-folded per-tap bases: c.w + CW[iy] + CW[ix]  (iy,ix symmetric).
    const float t0 = c.w + CW[0];
    const float t1 = c.w + CW[1];
    const float t2 = c.w + CW[2];
    v2f base[3][3];
    base[0][0] = (v2f){ t0 + CW[0], 0.0f };
    base[0][1] = (v2f){ t0 + CW[1], 0.0f };
    base[0][2] = (v2f){ t0 + CW[2], 0.0f };
    base[1][0] = (v2f){ t1 + CW[0], 0.0f };
    base[1][1] = (v2f){ t1 + CW[1], 0.0f };
    base[1][2] = (v2f){ t1 + CW[2], 0.0f };
    base[2][0] = (v2f){ t2 + CW[0], 0.0f };
    base[2][1] = (v2f){ t2 + CW[1], 0.0f };
    base[2][2] = (v2f){ t2 + CW[2], 0.0f };

    v2f nxy   = (v2f){ 0.0f, 0.0f };
    v2f nzden = (v2f){ 0.0f, 0.0f };

    #pragma unroll
    for (int dy = 0; dy < 5; ++dy) {
        const int iy = (dy < 3) ? dy : 4 - dy;
        #pragma unroll
        for (int k = 0; k < 5; ++k) {
            const int ix = (k < 3) ? k : 4 - k;
            const float4 s = lds[rp + dy][tx + k];
            const v2f sxy = (v2f){ s.x, s.y };
            const v2f szw = (v2f){ s.z, s.w };
            // q = [2cz*sz + base, s.w] ; p = [2cx*sx + q.x, 2cy*sy + q.y]
            const v2f q = __builtin_elementwise_fma(szw, c2z1, base[iy][ix]);
            const v2f p = __builtin_elementwise_fma(sxy, c01, q);
            const float w = EXP2(p.x + p.y);
            const v2f w2 = (v2f){ w, w };
            nxy   = __builtin_elementwise_fma(w2, sxy, nxy);
            nzden = __builtin_elementwise_fma(w2, (v2f){ s.z, 1.0f }, nzden);
        }
    }

    const float inv = RCP(nzden.y * S);
    const int y = by + rp;
    const int x = bx + tx;
    float* dst = out + ((size_t)(b * IMG_H + y) * IMG_W + x) * CH;
    dst[0] = fminf(fmaxf(nxy.x   * inv, 0.0f), 1.0f);
    dst[1] = fminf(fmaxf(nxy.y   * inv, 0.0f), 1.0f);
    dst[2] = fminf(fmaxf(nzden.x * inv, 0.0f), 1.0f);
}

extern "C" void kernel_launch(void* const* d_in, const int* in_sizes, int n_in,
                              void* d_out, int out_size, void* d_ws, size_t ws_size,
                              hipStream_t stream) {
    const float* in = (const float*)d_in[0];
    float* out = (float*)d_out;
    const int B = in_sizes[0] / (IMG_H * IMG_W * CH);   // 16

    dim3 block(TILE, TILE, 1);
    dim3 grid(IMG_W / TILE, IMG_H / TILE, B);           // 32 x 32 x 16
    bilateral_kernel<<<grid, block, 0, stream>>>(in, out);
}

// Round 10
// 40.368 us; speedup vs baseline: 1.4564x; 1.0537x over previous
//
#include <hip/hip_runtime.h>
#include <math.h>

#define IMG_H 512
#define IMG_W 512
#define CH    3
#define TILE  16
#define PAD   2
#define TP    (TILE + 2 * PAD)   // 20

#if __has_builtin(__builtin_amdgcn_exp2f)
#define EXP2(x) __builtin_amdgcn_exp2f(x)
#else
#define EXP2(x) exp2f(x)
#endif

#if __has_builtin(__builtin_amdgcn_rcpf)
#define RCP(x) __builtin_amdgcn_rcpf(x)
#else
#define RCP(x) (1.0f / (x))
#endif

__device__ __forceinline__ int reflect_idx(int i, int n) {
    i = (i < 0) ? -i : i;
    i = (i >= n) ? (2 * n - 2 - i) : i;
    return i;
}

__global__ __launch_bounds__(256)
void bilateral_kernel(const float* __restrict__ in, float* __restrict__ out) {
    // Entry: {r*S, g*S, b*S, -||s*S||^2}, S^2 = 312.5 * log2(e).
    // Conflict-free law (R3/R6 measured 0): wave's four 16-lane groups read
    // rows 4 apart at stride 20 float4, via the rp permutation.
    __shared__ float4 lds[TP][TP];

    const float S = sqrtf(312.5f * 1.44269504088896f);  // compile-time folded

    const int b  = blockIdx.z;
    const int by = blockIdx.y * TILE;
    const int bx = blockIdx.x * TILE;
    const int tx = threadIdx.x;
    const int ty = threadIdx.y;
    const int tid = ty * TILE + tx;

    // Cooperative halo staging with reflect padding (400 entries, 2 iters).
    for (int i = tid; i < TP * TP; i += 256) {
        const int py = i / TP;
        const int px = i - py * TP;
        const int gy = reflect_idx(by + py - PAD, IMG_H);
        const int gx = reflect_idx(bx + px - PAD, IMG_W);
        const float* src = in + ((size_t)(b * IMG_H + gy) * IMG_W + gx) * CH;
        const float s0 = src[0] * S;
        const float s1 = src[1] * S;
        const float s2 = src[2] * S;
        const float mq = -fmaf(s0, s0, fmaf(s1, s1, s2 * s2));
        ((float4*)lds)[i] = make_float4(s0, s1, s2, mq);
    }
    __syncthreads();

    // Row permutation: ty 0..3 -> rows 0,4,8,12 within each wave.
    const int rp = ((ty & 3) << 2) | (ty >> 2);

    // log2 of normalized 1-D gaussian weights, index min(d, 4-d).
    const float CW[3] = { -4.1978935f, -2.0338538f, -1.3125121f };

    const float4 c = lds[rp + PAD][tx + PAD];
    const float c2x = c.x + c.x;
    const float c2y = c.y + c.y;
    const float c2z = c.z + c.z;

    // 9 fully-folded per-tap bases: c.w + CW[iy] + CW[ix]  (scalars, static).
    const float t0 = c.w + CW[0];
    const float t1 = c.w + CW[1];
    const float t2 = c.w + CW[2];
    const float b00 = t0 + CW[0], b01 = t0 + CW[1], b02 = t0 + CW[2];
    const float b11 = t1 + CW[1], b12 = t1 + CW[2];
    const float b22 = t2 + CW[2];
    const float base[3][3] = {
        { b00, b01, b02 },
        { b01, b11, b12 },
        { b02, b12, b22 },
    };

    float n0 = 0.0f, n1 = 0.0f, n2 = 0.0f, den = 0.0f;

    #pragma unroll
    for (int dy = 0; dy < 5; ++dy) {
        const int iy = (dy < 3) ? dy : 4 - dy;
        #pragma unroll
        for (int k = 0; k < 5; ++k) {
            const int ix = (k < 3) ? k : 4 - k;
            const float4 s = lds[rp + dy][tx + k];
            // arg = 2c·s - ||s||^2 - ||c||^2 + log2(w_spatial), all in exp2 domain
            float t = fmaf(s.z, c2z, s.w);
            t = fmaf(s.y, c2y, t);
            t = fmaf(s.x, c2x, t);
            const float w = EXP2(t + base[iy][ix]);
            n0 = fmaf(w, s.x, n0);
            n1 = fmaf(w, s.y, n1);
            n2 = fmaf(w, s.z, n2);
            den += w;
        }
    }

    const float inv = RCP(den * S);
    const int y = by + rp;
    const int x = bx + tx;
    float* dst = out + ((size_t)(b * IMG_H + y) * IMG_W + x) * CH;
    dst[0] = fminf(fmaxf(n0 * inv, 0.0f), 1.0f);
    dst[1] = fminf(fmaxf(n1 * inv, 0.0f), 1.0f);
    dst[2] = fminf(fmaxf(n2 * inv, 0.0f), 1.0f);
}

extern "C" void kernel_launch(void* const* d_in, const int* in_sizes, int n_in,
                              void* d_out, int out_size, void* d_ws, size_t ws_size,
                              hipStream_t stream) {
    const float* in = (const float*)d_in[0];
    float* out = (float*)d_out;
    const int B = in_sizes[0] / (IMG_H * IMG_W * CH);   // 16

    dim3 block(TILE, TILE, 1);
    dim3 grid(IMG_W / TILE, IMG_H / TILE, B);           // 32 x 32 x 16
    bilateral_kernel<<<grid, block, 0, stream>>>(in, out);
}

// Round 12
// 38.236 us; speedup vs baseline: 1.5376x; 1.0558x over previous
//
#include <hip/hip_runtime.h>
#include <math.h>

#define IMG_H 512
#define IMG_W 512
#define CH    3
#define TILE_W 16
#define TILE_H 32
#define HALF  16
#define PAD   2
#define TP    20                 // padded per-half tile: 20 rows x 20 cols

typedef float v2f __attribute__((ext_vector_type(2)));
typedef float v4f __attribute__((ext_vector_type(4)));

#if __has_builtin(__builtin_amdgcn_exp2f)
#define EXP2(x) __builtin_amdgcn_exp2f(x)
#else
#define EXP2(x) exp2f(x)
#endif

#if __has_builtin(__builtin_amdgcn_rcpf)
#define RCP(x) __builtin_amdgcn_rcpf(x)
#else
#define RCP(x) (1.0f / (x))
#endif

__device__ __forceinline__ int reflect_idx(int i, int n) {
    i = (i < 0) ? -i : i;
    i = (i >= n) ? (2 * n - 2 - i) : i;
    return i;
}

__global__ __launch_bounds__(256)
void bilateral_kernel(const float* __restrict__ in, float* __restrict__ out) {
    // Two pixels per thread, HALF=16 rows apart; channels interleaved so every
    // v2f operand is a naturally-aligned VGPR pair (no marshaling movs):
    //   planeP[r][c] = (xA, xB, yA, yB)   planeQ[r][c] = (zA, zB, wA, wB)
    // A = padded row r, B = padded row r+16, w = -||s*S||^2.
    // All packed math via vector IR -> compiler emits v_pk_fma_f32/v_pk_add_f32
    // with correct VOP3P modifiers (R11's hand asm had them wrong).
    // Both planes are 20x20 float4 -> R3/R6-proven conflict-free geometry.
    __shared__ v4f planeP[TP][TP];
    __shared__ v4f planeQ[TP][TP];

    const float S = sqrtf(312.5f * 1.44269504088896f);  // compile-time folded

    const int b  = blockIdx.z;
    const int by = blockIdx.y * TILE_H;
    const int bx = blockIdx.x * TILE_W;
    const int tx = threadIdx.x;
    const int ty = threadIdx.y;
    const int tid = ty * TILE_W + tx;

    // Staging: 400 entries, each covers two pixels (rows r and r+16).
    for (int i = tid; i < TP * TP; i += 256) {
        const int r  = i / TP;
        const int cc = i - r * TP;
        const int gyA = reflect_idx(by + r - PAD, IMG_H);
        const int gyB = reflect_idx(by + HALF + r - PAD, IMG_H);
        const int gx  = reflect_idx(bx + cc - PAD, IMG_W);
        const float* pA = in + ((size_t)(b * IMG_H + gyA) * IMG_W + gx) * CH;
        const float* pB = in + ((size_t)(b * IMG_H + gyB) * IMG_W + gx) * CH;
        const float a0 = pA[0] * S, a1 = pA[1] * S, a2 = pA[2] * S;
        const float e0 = pB[0] * S, e1 = pB[1] * S, e2 = pB[2] * S;
        const float wA = -fmaf(a0, a0, fmaf(a1, a1, a2 * a2));
        const float wB = -fmaf(e0, e0, fmaf(e1, e1, e2 * e2));
        planeP[r][cc] = (v4f){ a0, e0, a1, e1 };
        planeQ[r][cc] = (v4f){ a2, e2, wA, wB };
    }
    __syncthreads();

    // Row permutation: ty 0..3 -> rows 0,4,8,12 within each wave (conflict-free).
    const int rp = ((ty & 3) << 2) | (ty >> 2);

    // log2 of normalized 1-D gaussian weights, index min(d, 4-d).
    const float CW[3] = { -4.1978935f, -2.0338538f, -1.3125121f };

    const v4f cP = planeP[rp + PAD][tx + PAD];
    const v4f cQ = planeQ[rp + PAD][tx + PAD];
    const v2f c2x = __builtin_shufflevector(cP, cP, 0, 1) + __builtin_shufflevector(cP, cP, 0, 1);
    const v2f c2y = __builtin_shufflevector(cP, cP, 2, 3) + __builtin_shufflevector(cP, cP, 2, 3);
    const v2f c2z = __builtin_shufflevector(cQ, cQ, 0, 1) + __builtin_shufflevector(cQ, cQ, 0, 1);
    const v2f cw  = __builtin_shufflevector(cQ, cQ, 2, 3);

    // 9 prefolded pair-bases: cw + CW[iy] + CW[ix]  (compile-time CW sums).
    v2f base[3][3];
    #pragma unroll
    for (int iy = 0; iy < 3; ++iy)
        #pragma unroll
        for (int ix = 0; ix < 3; ++ix) {
            const float k = CW[iy] + CW[ix];
            base[iy][ix] = cw + (v2f){ k, k };
        }

    v2f nx = (v2f){0.f,0.f}, ny = (v2f){0.f,0.f};
    v2f nz = (v2f){0.f,0.f}, nd = (v2f){0.f,0.f};

    #pragma unroll
    for (int dy = 0; dy < 5; ++dy) {
        const int iy = (dy < 3) ? dy : 4 - dy;
        #pragma unroll
        for (int k = 0; k < 5; ++k) {
            const int ix = (k < 3) ? k : 4 - k;
            const v4f P = planeP[rp + dy][tx + k];
            const v4f Q = planeQ[rp + dy][tx + k];
            const v2f sx = __builtin_shufflevector(P, P, 0, 1);
            const v2f sy = __builtin_shufflevector(P, P, 2, 3);
            const v2f sz = __builtin_shufflevector(Q, Q, 0, 1);
            const v2f sw = __builtin_shufflevector(Q, Q, 2, 3);
            // arg = 2c.s - ||s||^2 - ||c||^2 + log2(w_spatial)  (exp2 domain)
            v2f t = sw + base[iy][ix];
            t = __builtin_elementwise_fma(sz, c2z, t);
            t = __builtin_elementwise_fma(sy, c2y, t);
            t = __builtin_elementwise_fma(sx, c2x, t);
            const v2f w = (v2f){ EXP2(t.x), EXP2(t.y) };
            nx = __builtin_elementwise_fma(w, sx, nx);
            ny = __builtin_elementwise_fma(w, sy, ny);
            nz = __builtin_elementwise_fma(w, sz, nz);
            nd = nd + w;
        }
    }

    const int xcol = bx + tx;
    {
        const float inv = RCP(nd.x * S);
        float* dst = out + ((size_t)(b * IMG_H + by + rp) * IMG_W + xcol) * CH;
        dst[0] = fminf(fmaxf(nx.x * inv, 0.0f), 1.0f);
        dst[1] = fminf(fmaxf(ny.x * inv, 0.0f), 1.0f);
        dst[2] = fminf(fmaxf(nz.x * inv, 0.0f), 1.0f);
    }
    {
        const float inv = RCP(nd.y * S);
        float* dst = out + ((size_t)(b * IMG_H + by + HALF + rp) * IMG_W + xcol) * CH;
        dst[0] = fminf(fmaxf(nx.y * inv, 0.0f), 1.0f);
        dst[1] = fminf(fmaxf(ny.y * inv, 0.0f), 1.0f);
        dst[2] = fminf(fmaxf(nz.y * inv, 0.0f), 1.0f);
    }
}

extern "C" void kernel_launch(void* const* d_in, const int* in_sizes, int n_in,
                              void* d_out, int out_size, void* d_ws, size_t ws_size,
                              hipStream_t stream) {
    const float* in = (const float*)d_in[0];
    float* out = (float*)d_out;
    const int B = in_sizes[0] / (IMG_H * IMG_W * CH);   // 16

    dim3 block(TILE_W, 16, 1);
    dim3 grid(IMG_W / TILE_W, IMG_H / TILE_H, B);       // 32 x 16 x 16
    bilateral_kernel<<<grid, block, 0, stream>>>(in, out);
}